// Round 2
// baseline (3825.073 us; speedup 1.0000x reference)
//
#include <hip/hip_runtime.h>
#include <hip/hip_bf16.h>
#include <stdint.h>

typedef __hip_bfloat16 bf16;

#define DIMN 128
#define NBLK 8      // rows per block
#define EPSLN 1e-5f

__device__ __forceinline__ float b2f(bf16 x) { return __bfloat162float(x); }
__device__ __forceinline__ bf16  f2b(float x) { return __float2bfloat16(x); }
__device__ __forceinline__ float sigm(float x) { return 1.0f / (1.0f + __expf(-x)); }

// dtype-generic load of element i from a float-ish tensor
template<int F32>
__device__ __forceinline__ float ld(const void* p, size_t i) {
    if (F32) return ((const float*)p)[i];
    else     return b2f(((const bf16*)p)[i]);
}
// dtype-generic store
template<int F32>
__device__ __forceinline__ void st(void* p, size_t i, float v) {
    if (F32) ((float*)p)[i] = v;
    else     ((bf16*)p)[i]  = f2b(v);
}

// ---------------------------------------------------------------------------
// Detector: distinguish f32 buffer from packed-bf16 buffer using LOW 16 bits
// of each 32-bit word. bf16 is truncated f32, so high halves look identical;
// low halves are uniform mantissa bits (f32) vs a bf16 value whose exponent
// concentrates in [90,140] (bf16-packed N(0,1) data).
// ---------------------------------------------------------------------------
__global__ void detect_dtype_kernel(const uint32_t* __restrict__ w, int* __restrict__ flag) {
    if (threadIdx.x == 0 && blockIdx.x == 0) {
        int c = 0;
        for (int i = 0; i < 64; ++i) {
            uint32_t lo = w[i] & 0xFFFFu;
            int e = (int)((lo >> 7) & 0xFF);
            if (e >= 90 && e <= 140) ++c;
        }
        // bf16-packed: c ~ 64.  f32: c ~ 12.
        *flag = (c < 32) ? 1 : 0;   // 1 => inputs/outputs are float32
    }
}

// ---------------------------------------------------------------------------
// Kernel A body: node projections
// ---------------------------------------------------------------------------
template<int F32>
__device__ void node_proj_body(
    const void* h,
    const void* w_src, const void* b_src,
    const void* w_dst, const void* b_dst,
    const void* w_msg, const void* b_msg,
    bf16* __restrict__ p_src, bf16* __restrict__ p_dst, float* __restrict__ p_msg,
    int n)
{
    __shared__ float xs[NBLK][DIMN];
    const int base = blockIdx.x * NBLK;
    const int tid = threadIdx.x;

    for (int idx = tid; idx < NBLK * DIMN; idx += 128) {
        int r = idx >> 7, c = idx & 127;
        int row = base + r;
        xs[r][c] = (row < n) ? ld<F32>(h, (size_t)row * DIMN + c) : 0.f;
    }
    __syncthreads();

    const int j = tid;
    float a0[NBLK], a1[NBLK], a2[NBLK];
#pragma unroll
    for (int r = 0; r < NBLK; ++r) { a0[r] = 0.f; a1[r] = 0.f; a2[r] = 0.f; }

#pragma unroll 4
    for (int k = 0; k < DIMN; ++k) {
        float ws_ = ld<F32>(w_src, k * DIMN + j);
        float wd_ = ld<F32>(w_dst, k * DIMN + j);
        float wm_ = ld<F32>(w_msg, k * DIMN + j);
#pragma unroll
        for (int r = 0; r < NBLK; ++r) {
            float x = xs[r][k];
            a0[r] += x * ws_;
            a1[r] += x * wd_;
            a2[r] += x * wm_;
        }
    }

    float bs = ld<F32>(b_src, j), bd = ld<F32>(b_dst, j), bm = ld<F32>(b_msg, j);
#pragma unroll
    for (int r = 0; r < NBLK; ++r) {
        int row = base + r;
        if (row < n) {
            size_t o = (size_t)row * DIMN + j;
            p_src[o] = f2b(a0[r] + bs);
            p_dst[o] = f2b(a1[r] + bd);
            p_msg[o] = a2[r] + bm;
        }
    }
}

__global__ void __launch_bounds__(128) node_proj_kernel(
    const int* __restrict__ flag,
    const void* h, const void* w_src, const void* b_src,
    const void* w_dst, const void* b_dst, const void* w_msg, const void* b_msg,
    bf16* p_src, bf16* p_dst, float* p_msg, int n)
{
    if (*flag) node_proj_body<1>(h, w_src, b_src, w_dst, b_dst, w_msg, b_msg, p_src, p_dst, p_msg, n);
    else       node_proj_body<0>(h, w_src, b_src, w_dst, b_dst, w_msg, b_msg, p_src, p_dst, p_msg, n);
}

// ---------------------------------------------------------------------------
// Kernel B body: per-edge gate + message, atomic scatter-add into agg
// ---------------------------------------------------------------------------
template<int F32>
__device__ void edge_gate_body(
    const void* e,
    const int* __restrict__ src, const int* __restrict__ dst,
    const void* w_eg, const void* b_eg,
    const bf16* __restrict__ p_src, const bf16* __restrict__ p_dst,
    const float* __restrict__ p_msg,
    float* __restrict__ agg, int ne)
{
    __shared__ float xs[NBLK][DIMN];
    __shared__ int sidx[NBLK], didx[NBLK];
    const int base = blockIdx.x * NBLK;
    const int tid = threadIdx.x;

    if (tid < NBLK) {
        int eid = base + tid;
        sidx[tid] = (eid < ne) ? src[eid] : 0;
        didx[tid] = (eid < ne) ? dst[eid] : 0;
    }
    for (int idx = tid; idx < NBLK * DIMN; idx += 128) {
        int r = idx >> 7, c = idx & 127;
        int eid = base + r;
        xs[r][c] = (eid < ne) ? ld<F32>(e, (size_t)eid * DIMN + c) : 0.f;
    }
    __syncthreads();

    const int j = tid;
    float acc[NBLK];
#pragma unroll
    for (int r = 0; r < NBLK; ++r) acc[r] = 0.f;

#pragma unroll 4
    for (int k = 0; k < DIMN; ++k) {
        float w = ld<F32>(w_eg, k * DIMN + j);
#pragma unroll
        for (int r = 0; r < NBLK; ++r) acc[r] += xs[r][k] * w;
    }

    float bias = ld<F32>(b_eg, j);
#pragma unroll
    for (int r = 0; r < NBLK; ++r) {
        int eid = base + r;
        if (eid < ne) {
            int s = sidx[r], d = didx[r];
            float gl = acc[r] + bias + b2f(p_src[(size_t)s * DIMN + j]) + b2f(p_dst[(size_t)d * DIMN + j]);
            float m = sigm(gl) * p_msg[(size_t)s * DIMN + j];
            atomicAdd(&agg[(size_t)d * DIMN + j], m);
        }
    }
}

__global__ void __launch_bounds__(128) edge_gate_kernel(
    const int* __restrict__ flag,
    const void* e, const int* src, const int* dst,
    const void* w_eg, const void* b_eg,
    const bf16* p_src, const bf16* p_dst, const float* p_msg,
    float* agg, int ne)
{
    if (*flag) edge_gate_body<1>(e, src, dst, w_eg, b_eg, p_src, p_dst, p_msg, agg, ne);
    else       edge_gate_body<0>(e, src, dst, w_eg, b_eg, p_src, p_dst, p_msg, agg, ne);
}

// ---------------------------------------------------------------------------
// Kernel C body: node update
// ---------------------------------------------------------------------------
template<int F32>
__device__ void node_update_body(
    const void* h, const float* __restrict__ agg,
    const void* w_n1, const void* b_n1,
    const void* w_n2, const void* b_n2,
    const void* g_n, const void* bt_n,
    void* out, int n)
{
    __shared__ float xs[NBLK][2 * DIMN];
    __shared__ float u1[NBLK][DIMN];
    __shared__ float xv[NBLK][DIMN];
    __shared__ float mu_s[NBLK], rs_s[NBLK];
    const int base = blockIdx.x * NBLK;
    const int tid = threadIdx.x;

    for (int idx = tid; idx < NBLK * DIMN; idx += 128) {
        int r = idx >> 7, c = idx & 127;
        int row = base + r;
        xs[r][c]        = (row < n) ? ld<F32>(h, (size_t)row * DIMN + c) : 0.f;
        xs[r][DIMN + c] = (row < n) ? agg[(size_t)row * DIMN + c] : 0.f;
    }
    __syncthreads();

    const int j = tid;
    float acc[NBLK];
#pragma unroll
    for (int r = 0; r < NBLK; ++r) acc[r] = 0.f;
#pragma unroll 4
    for (int k = 0; k < 2 * DIMN; ++k) {
        float w = ld<F32>(w_n1, k * DIMN + j);
#pragma unroll
        for (int r = 0; r < NBLK; ++r) acc[r] += xs[r][k] * w;
    }
    float b1 = ld<F32>(b_n1, j);
#pragma unroll
    for (int r = 0; r < NBLK; ++r) {
        float u = acc[r] + b1;
        u1[r][j] = u * sigm(u);
    }
    __syncthreads();

#pragma unroll
    for (int r = 0; r < NBLK; ++r) acc[r] = 0.f;
#pragma unroll 4
    for (int k = 0; k < DIMN; ++k) {
        float w = ld<F32>(w_n2, k * DIMN + j);
#pragma unroll
        for (int r = 0; r < NBLK; ++r) acc[r] += u1[r][k] * w;
    }
    float b2 = ld<F32>(b_n2, j);
#pragma unroll
    for (int r = 0; r < NBLK; ++r) {
        xv[r][j] = xs[r][j] + acc[r] + b2;   // residual h + nu
    }
    __syncthreads();

    {
        int r = tid >> 4, l = tid & 15;
        float s = 0.f, s2 = 0.f;
        for (int c = l; c < DIMN; c += 16) {
            float v = xv[r][c];
            s += v; s2 += v * v;
        }
#pragma unroll
        for (int off = 8; off > 0; off >>= 1) {
            s  += __shfl_down(s, off, 16);
            s2 += __shfl_down(s2, off, 16);
        }
        if (l == 0) {
            float mu = s / DIMN;
            float var = s2 / DIMN - mu * mu;
            mu_s[r] = mu;
            rs_s[r] = rsqrtf(var + EPSLN);
        }
    }
    __syncthreads();

    float gg = ld<F32>(g_n, j), bb = ld<F32>(bt_n, j);
#pragma unroll
    for (int r = 0; r < NBLK; ++r) {
        int row = base + r;
        if (row < n)
            st<F32>(out, (size_t)row * DIMN + j, (xv[r][j] - mu_s[r]) * rs_s[r] * gg + bb);
    }
}

__global__ void __launch_bounds__(128) node_update_kernel(
    const int* __restrict__ flag,
    const void* h, const float* agg,
    const void* w_n1, const void* b_n1, const void* w_n2, const void* b_n2,
    const void* g_n, const void* bt_n, void* out, int n)
{
    if (*flag) node_update_body<1>(h, agg, w_n1, b_n1, w_n2, b_n2, g_n, bt_n, out, n);
    else       node_update_body<0>(h, agg, w_n1, b_n1, w_n2, b_n2, g_n, bt_n, out, n);
}

// ---------------------------------------------------------------------------
// Kernel D body: edge update
// ---------------------------------------------------------------------------
template<int F32>
__device__ void edge_update_body(
    const void* e,
    const int* __restrict__ src, const int* __restrict__ dst,
    const float* __restrict__ p_msg,
    const void* w_e1, const void* b_e1,
    const void* w_e2, const void* b_e2,
    const void* g_e, const void* bt_e,
    void* out, size_t obase, int ne)
{
    __shared__ float xs[NBLK][3 * DIMN];
    __shared__ float u1[NBLK][DIMN];
    __shared__ float mu_s[NBLK], rs_s[NBLK];
    __shared__ int sidx[NBLK], didx[NBLK];
    const int base = blockIdx.x * NBLK;
    const int tid = threadIdx.x;

    if (tid < NBLK) {
        int eid = base + tid;
        sidx[tid] = (eid < ne) ? src[eid] : 0;
        didx[tid] = (eid < ne) ? dst[eid] : 0;
    }
    __syncthreads();

    for (int idx = tid; idx < NBLK * DIMN; idx += 128) {
        int r = idx >> 7, c = idx & 127;
        int eid = base + r;
        int s = sidx[r], d = didx[r];
        xs[r][c]            = (eid < ne) ? ld<F32>(e, (size_t)eid * DIMN + c) : 0.f;
        xs[r][DIMN + c]     = (eid < ne) ? p_msg[(size_t)s * DIMN + c] : 0.f;
        xs[r][2 * DIMN + c] = (eid < ne) ? p_msg[(size_t)d * DIMN + c] : 0.f;
    }
    __syncthreads();

    const int j = tid;
    float acc[NBLK];
#pragma unroll
    for (int r = 0; r < NBLK; ++r) acc[r] = 0.f;
#pragma unroll 4
    for (int k = 0; k < 3 * DIMN; ++k) {
        float w = ld<F32>(w_e1, k * DIMN + j);
#pragma unroll
        for (int r = 0; r < NBLK; ++r) acc[r] += xs[r][k] * w;
    }
    float b1 = ld<F32>(b_e1, j);
#pragma unroll
    for (int r = 0; r < NBLK; ++r) {
        float u = acc[r] + b1;
        u1[r][j] = u * sigm(u);
    }
    __syncthreads();

#pragma unroll
    for (int r = 0; r < NBLK; ++r) acc[r] = 0.f;
#pragma unroll 4
    for (int k = 0; k < DIMN; ++k) {
        float w = ld<F32>(w_e2, k * DIMN + j);
#pragma unroll
        for (int r = 0; r < NBLK; ++r) acc[r] += u1[r][k] * w;
    }
    float b2 = ld<F32>(b_e2, j);
    __syncthreads();   // all reads of u1 done before overwrite
#pragma unroll
    for (int r = 0; r < NBLK; ++r) {
        u1[r][j] = xs[r][j] + acc[r] + b2;   // residual e + eu
    }
    __syncthreads();

    {
        int r = tid >> 4, l = tid & 15;
        float s = 0.f, s2 = 0.f;
        for (int c = l; c < DIMN; c += 16) {
            float v = u1[r][c];
            s += v; s2 += v * v;
        }
#pragma unroll
        for (int off = 8; off > 0; off >>= 1) {
            s  += __shfl_down(s, off, 16);
            s2 += __shfl_down(s2, off, 16);
        }
        if (l == 0) {
            float mu = s / DIMN;
            float var = s2 / DIMN - mu * mu;
            mu_s[r] = mu;
            rs_s[r] = rsqrtf(var + EPSLN);
        }
    }
    __syncthreads();

    float gg = ld<F32>(g_e, j), bb = ld<F32>(bt_e, j);
#pragma unroll
    for (int r = 0; r < NBLK; ++r) {
        int eid = base + r;
        if (eid < ne)
            st<F32>(out, obase + (size_t)eid * DIMN + j, (u1[r][j] - mu_s[r]) * rs_s[r] * gg + bb);
    }
}

__global__ void __launch_bounds__(128) edge_update_kernel(
    const int* __restrict__ flag,
    const void* e, const int* src, const int* dst, const float* p_msg,
    const void* w_e1, const void* b_e1, const void* w_e2, const void* b_e2,
    const void* g_e, const void* bt_e, void* out, size_t obase, int ne)
{
    if (*flag) edge_update_body<1>(e, src, dst, p_msg, w_e1, b_e1, w_e2, b_e2, g_e, bt_e, out, obase, ne);
    else       edge_update_body<0>(e, src, dst, p_msg, w_e1, b_e1, w_e2, b_e2, g_e, bt_e, out, obase, ne);
}

// ---------------------------------------------------------------------------
extern "C" void kernel_launch(void* const* d_in, const int* in_sizes, int n_in,
                              void* d_out, int out_size, void* d_ws, size_t ws_size,
                              hipStream_t stream)
{
    const void* h     = d_in[0];
    const void* e     = d_in[1];
    const int*  src   = (const int*)d_in[2];
    const int*  dst   = (const int*)d_in[3];
    const void* w_src = d_in[4];
    const void* b_src = d_in[5];
    const void* w_dst = d_in[6];
    const void* b_dst = d_in[7];
    const void* w_eg  = d_in[8];
    const void* b_eg  = d_in[9];
    const void* w_msg = d_in[10];
    const void* b_msg = d_in[11];
    const void* w_n1  = d_in[12];
    const void* b_n1  = d_in[13];
    const void* w_n2  = d_in[14];
    const void* b_n2  = d_in[15];
    const void* w_e1  = d_in[16];
    const void* b_e1  = d_in[17];
    const void* w_e2  = d_in[18];
    const void* b_e2  = d_in[19];
    const void* g_n   = d_in[20];
    const void* bt_n  = d_in[21];
    const void* g_e   = d_in[22];
    const void* bt_e  = d_in[23];

    const int n  = in_sizes[0] / DIMN;   // 40000
    const int ne = in_sizes[1] / DIMN;   // 640000

    // workspace layout: p_src(bf16) p_dst(bf16) p_msg(f32) agg(f32) flag(int)
    bf16*  p_src = (bf16*)d_ws;
    bf16*  p_dst = p_src + (size_t)n * DIMN;
    float* p_msg = (float*)(p_dst + (size_t)n * DIMN);
    float* agg   = p_msg + (size_t)n * DIMN;
    int*   flag  = (int*)(agg + (size_t)n * DIMN);

    hipMemsetAsync(agg, 0, (size_t)n * DIMN * sizeof(float), stream);

    detect_dtype_kernel<<<1, 64, 0, stream>>>((const uint32_t*)h, flag);

    int nb_n = (n + NBLK - 1) / NBLK;
    int nb_e = (ne + NBLK - 1) / NBLK;

    node_proj_kernel<<<nb_n, 128, 0, stream>>>(
        flag, h, w_src, b_src, w_dst, b_dst, w_msg, b_msg, p_src, p_dst, p_msg, n);

    edge_gate_kernel<<<nb_e, 128, 0, stream>>>(
        flag, e, src, dst, w_eg, b_eg, p_src, p_dst, p_msg, agg, ne);

    node_update_kernel<<<nb_n, 128, 0, stream>>>(
        flag, h, agg, w_n1, b_n1, w_n2, b_n2, g_n, bt_n, d_out, n);

    edge_update_kernel<<<nb_e, 128, 0, stream>>>(
        flag, e, src, dst, p_msg, w_e1, b_e1, w_e2, b_e2, g_e, bt_e,
        d_out, (size_t)n * DIMN, ne);
}

// Round 3
// 2012.549 us; speedup vs baseline: 1.9006x; 1.9006x over previous
//
#include <hip/hip_runtime.h>
#include <hip/hip_bf16.h>
#include <stdint.h>

typedef __hip_bfloat16 bf16;
typedef __attribute__((ext_vector_type(8))) short short8;
typedef __attribute__((ext_vector_type(4))) float f32x4;

#define DIMN 128
#define NBLK 8
#define BM 64
#define EPSLN 1e-5f

__device__ __forceinline__ float b2f(bf16 x) { return __bfloat162float(x); }
__device__ __forceinline__ bf16  f2b(float x) { return __float2bfloat16(x); }
__device__ __forceinline__ float sigm(float x) { return 1.0f / (1.0f + __expf(-x)); }

__device__ __forceinline__ float bfb2f(unsigned short u) {
    union { uint32_t i; float f; } v; v.i = ((uint32_t)u) << 16; return v.f;
}
__device__ __forceinline__ unsigned short f2bfb(float f) {
    union { float f; uint32_t i; } v; v.f = f;
    uint32_t x = v.i;
    return (unsigned short)((x + 0x7FFFu + ((x >> 16) & 1u)) >> 16);
}

template<int F32>
__device__ __forceinline__ float ld(const void* p, size_t i) {
    if (F32) return ((const float*)p)[i];
    else     return bfb2f(((const unsigned short*)p)[i]);
}
template<int F32>
__device__ __forceinline__ void st(void* p, size_t i, float v) {
    if (F32) ((float*)p)[i] = v;
    else     ((unsigned short*)p)[i] = f2bfb(v);
}
template<int F32>
__device__ __forceinline__ void load8(const void* p, size_t elem, float v[8]) {
    if (F32) {
        const float4* q = (const float4*)((const float*)p + elem);
        float4 a = q[0], b = q[1];
        v[0]=a.x; v[1]=a.y; v[2]=a.z; v[3]=a.w;
        v[4]=b.x; v[5]=b.y; v[6]=b.z; v[7]=b.w;
    } else {
        short8 s = *(const short8*)((const short*)p + elem);
#pragma unroll
        for (int j = 0; j < 8; ++j) v[j] = bfb2f((unsigned short)s[j]);
    }
}

// X tile: [64 rows][384 k] bf16, row stride 768 B, XOR-swizzled 16B units
__device__ __forceinline__ uint32_t xaddr(int r, int k) {
    return (uint32_t)(r * 768 + ((k * 2) ^ ((r & 7) << 4)));
}
// u tile lives in X's segment-2 bytes [512,768) per row
__device__ __forceinline__ uint32_t uaddr(int r, int k) {
    return (uint32_t)(r * 768 + 512 + ((k * 2) ^ ((r & 7) << 4)));
}

// ---------------------------------------------------------------------------
// dtype detector (low 16 bits of f32 words look uniform; packed-bf16 doesn't)
// ---------------------------------------------------------------------------
__global__ void detect_dtype_kernel(const uint32_t* __restrict__ w, int* __restrict__ flag) {
    if (threadIdx.x == 0 && blockIdx.x == 0) {
        int c = 0;
        for (int i = 0; i < 64; ++i) {
            uint32_t lo = w[i] & 0xFFFFu;
            int e = (int)((lo >> 7) & 0xFF);
            if (e >= 90 && e <= 140) ++c;
        }
        *flag = (c < 32) ? 1 : 0;   // 1 => float32 tensors
    }
}

// ---------------------------------------------------------------------------
// weight prep: transpose + bf16-ify  wT[c][k] = w[k][c]
// ---------------------------------------------------------------------------
template<int F32>
__device__ void prep_body(const void* w_eg, const void* w_e1, const void* w_e2,
                          unsigned short* wtg, unsigned short* wt1, unsigned short* wt2)
{
    int idx = blockIdx.x * 256 + threadIdx.x;
    if (idx < 128 * 384) {
        int c = idx / 384, k = idx % 384;
        wt1[idx] = f2bfb(ld<F32>(w_e1, (size_t)k * 128 + c));
    }
    if (idx < 128 * 128) {
        int c = idx >> 7, k = idx & 127;
        wtg[idx] = f2bfb(ld<F32>(w_eg, (size_t)k * 128 + c));
        wt2[idx] = f2bfb(ld<F32>(w_e2, (size_t)k * 128 + c));
    }
}
__global__ void __launch_bounds__(256) prep_weights_kernel(
    const int* __restrict__ flag,
    const void* w_eg, const void* w_e1, const void* w_e2,
    unsigned short* wtg, unsigned short* wt1, unsigned short* wt2)
{
    if (*flag) prep_body<1>(w_eg, w_e1, w_e2, wtg, wt1, wt2);
    else       prep_body<0>(w_eg, w_e1, w_e2, wtg, wt1, wt2);
}

// ---------------------------------------------------------------------------
// node projections (round-2, known good)
// ---------------------------------------------------------------------------
template<int F32>
__device__ void node_proj_body(
    const void* h, const void* w_src, const void* b_src,
    const void* w_dst, const void* b_dst, const void* w_msg, const void* b_msg,
    bf16* __restrict__ p_src, bf16* __restrict__ p_dst, float* __restrict__ p_msg, int n)
{
    __shared__ float xs[NBLK][DIMN];
    const int base = blockIdx.x * NBLK;
    const int tid = threadIdx.x;

    for (int idx = tid; idx < NBLK * DIMN; idx += 128) {
        int r = idx >> 7, c = idx & 127;
        int row = base + r;
        xs[r][c] = (row < n) ? ld<F32>(h, (size_t)row * DIMN + c) : 0.f;
    }
    __syncthreads();

    const int j = tid;
    float a0[NBLK], a1[NBLK], a2[NBLK];
#pragma unroll
    for (int r = 0; r < NBLK; ++r) { a0[r] = 0.f; a1[r] = 0.f; a2[r] = 0.f; }

#pragma unroll 4
    for (int k = 0; k < DIMN; ++k) {
        float ws_ = ld<F32>(w_src, k * DIMN + j);
        float wd_ = ld<F32>(w_dst, k * DIMN + j);
        float wm_ = ld<F32>(w_msg, k * DIMN + j);
#pragma unroll
        for (int r = 0; r < NBLK; ++r) {
            float x = xs[r][k];
            a0[r] += x * ws_; a1[r] += x * wd_; a2[r] += x * wm_;
        }
    }

    float bs = ld<F32>(b_src, j), bd = ld<F32>(b_dst, j), bm = ld<F32>(b_msg, j);
#pragma unroll
    for (int r = 0; r < NBLK; ++r) {
        int row = base + r;
        if (row < n) {
            size_t o = (size_t)row * DIMN + j;
            p_src[o] = f2b(a0[r] + bs);
            p_dst[o] = f2b(a1[r] + bd);
            p_msg[o] = a2[r] + bm;
        }
    }
}
__global__ void __launch_bounds__(128) node_proj_kernel(
    const int* __restrict__ flag,
    const void* h, const void* w_src, const void* b_src,
    const void* w_dst, const void* b_dst, const void* w_msg, const void* b_msg,
    bf16* p_src, bf16* p_dst, float* p_msg, int n)
{
    if (*flag) node_proj_body<1>(h, w_src, b_src, w_dst, b_dst, w_msg, b_msg, p_src, p_dst, p_msg, n);
    else       node_proj_body<0>(h, w_src, b_src, w_dst, b_dst, w_msg, b_msg, p_src, p_dst, p_msg, n);
}

// ---------------------------------------------------------------------------
// fused edge mega-kernel (MFMA): gate matmul + scatter + edge update
// ---------------------------------------------------------------------------
template<int F32>
__device__ void edge_mega_body(
    const void* e,
    const int* __restrict__ src, const int* __restrict__ dst,
    const bf16* __restrict__ p_src, const bf16* __restrict__ p_dst,
    const float* __restrict__ p_msg,
    const unsigned short* __restrict__ wtg,   // [128][128]
    const unsigned short* __restrict__ wt1,   // [128][384]
    const unsigned short* __restrict__ wt2,   // [128][128]
    const void* b_eg, const void* b_e1, const void* b_e2,
    const void* g_e, const void* bt_e,
    float* __restrict__ agg, void* out, size_t obase, int ne)
{
    __shared__ short xs_raw[BM * 384];      // 48 KB, swizzled; seg2 reused for u
    __shared__ int sidx[BM], didx[BM];
    __shared__ float sm_s[BM], sm_s2[BM], sm_mu[BM], sm_rs[BM];

    const int tid = threadIdx.x;
    const int base = blockIdx.x * BM;
    char* xs = (char*)xs_raw;

    if (tid < BM) {
        int eid = base + tid;
        sidx[tid] = (eid < ne) ? src[eid] : 0;
        didx[tid] = (eid < ne) ? dst[eid] : 0;
        sm_s[tid] = 0.f; sm_s2[tid] = 0.f;
    }
    __syncthreads();

    // ---- stage X = [e | p_msg[src] | p_msg[dst]] as bf16, swizzled ----
    for (int idx = tid; idx < BM * 48; idx += 256) {
        int r = idx / 48;
        int kc = (idx % 48) * 8;          // element offset in [0,384)
        int eid = base + r;
        float v[8];
        if (eid < ne) {
            if (kc < 128)       load8<F32>(e, (size_t)eid * 128 + kc, v);
            else if (kc < 256)  load8<1>(p_msg, (size_t)sidx[r] * 128 + (kc - 128), v);
            else                load8<1>(p_msg, (size_t)didx[r] * 128 + (kc - 256), v);
        } else {
#pragma unroll
            for (int j = 0; j < 8; ++j) v[j] = 0.f;
        }
        short8 pk;
#pragma unroll
        for (int j = 0; j < 8; ++j) pk[j] = (short)f2bfb(v[j]);
        *(short8*)(xs + xaddr(r, kc)) = pk;
    }
    __syncthreads();

    const int lane = tid & 63;
    const int wv = tid >> 6;            // wave 0..3 owns cols [wv*32, wv*32+32)
    const int l16 = lane & 15;
    const int lk = lane >> 4;           // 0..3
    const int colbase = wv * 32;

    f32x4 acc1[4][2], accg[4][2];
#pragma unroll
    for (int mf = 0; mf < 4; ++mf)
#pragma unroll
        for (int nf = 0; nf < 2; ++nf) {
            acc1[mf][nf] = (f32x4){0.f,0.f,0.f,0.f};
            accg[mf][nf] = (f32x4){0.f,0.f,0.f,0.f};
        }

    // ---- matmul1 (K=384) with gate matmul fused into K-steps 0..3 ----
    for (int kt = 0; kt < 12; ++kt) {
        int k0 = kt * 32;
        short8 a[4];
#pragma unroll
        for (int mf = 0; mf < 4; ++mf)
            a[mf] = *(const short8*)(xs + xaddr(mf * 16 + l16, k0 + lk * 8));
        short8 b0 = *(const short8*)(wt1 + ((size_t)(colbase + l16)      * 384 + k0 + lk * 8));
        short8 b1 = *(const short8*)(wt1 + ((size_t)(colbase + 16 + l16) * 384 + k0 + lk * 8));
#pragma unroll
        for (int mf = 0; mf < 4; ++mf) {
            acc1[mf][0] = __builtin_amdgcn_mfma_f32_16x16x32_bf16(a[mf], b0, acc1[mf][0], 0, 0, 0);
            acc1[mf][1] = __builtin_amdgcn_mfma_f32_16x16x32_bf16(a[mf], b1, acc1[mf][1], 0, 0, 0);
        }
        if (kt < 4) {
            short8 g0 = *(const short8*)(wtg + ((size_t)(colbase + l16)      * 128 + k0 + lk * 8));
            short8 g1 = *(const short8*)(wtg + ((size_t)(colbase + 16 + l16) * 128 + k0 + lk * 8));
#pragma unroll
            for (int mf = 0; mf < 4; ++mf) {
                accg[mf][0] = __builtin_amdgcn_mfma_f32_16x16x32_bf16(a[mf], g0, accg[mf][0], 0, 0, 0);
                accg[mf][1] = __builtin_amdgcn_mfma_f32_16x16x32_bf16(a[mf], g1, accg[mf][1], 0, 0, 0);
            }
        }
    }

    // ---- gate epilogue: sigmoid * msg, atomic scatter into agg ----
    {
        float bge[2] = { ld<F32>(b_eg, colbase + l16), ld<F32>(b_eg, colbase + 16 + l16) };
#pragma unroll
        for (int mf = 0; mf < 4; ++mf)
#pragma unroll
            for (int nf = 0; nf < 2; ++nf) {
                int col = colbase + nf * 16 + l16;
#pragma unroll
                for (int rr = 0; rr < 4; ++rr) {
                    int row = mf * 16 + lk * 4 + rr;
                    int eid = base + row;
                    int s = sidx[row], d = didx[row];
                    float g = accg[mf][nf][rr] + bge[nf]
                            + bfb2f(((const unsigned short*)p_src)[(size_t)s * 128 + col])
                            + bfb2f(((const unsigned short*)p_dst)[(size_t)d * 128 + col]);
                    unsigned short pm = *(const unsigned short*)(xs + (row * 768 + (((128 + col) * 2) ^ ((row & 7) << 4))));
                    float m = sigm(g) * bfb2f(pm);
                    if (eid < ne) atomicAdd(&agg[(size_t)d * 128 + col], m);
                }
            }
    }
    __syncthreads();   // all reads of X seg2 done (matmul1 + gate) before u overwrite

    // ---- silu, write u into X seg2 (bf16, swizzled) ----
    {
        float be1[2] = { ld<F32>(b_e1, colbase + l16), ld<F32>(b_e1, colbase + 16 + l16) };
#pragma unroll
        for (int mf = 0; mf < 4; ++mf)
#pragma unroll
            for (int nf = 0; nf < 2; ++nf) {
                int col = colbase + nf * 16 + l16;
#pragma unroll
                for (int rr = 0; rr < 4; ++rr) {
                    int row = mf * 16 + lk * 4 + rr;
                    float u = acc1[mf][nf][rr] + be1[nf];
                    u = u * sigm(u);
                    *(unsigned short*)(xs + uaddr(row, col)) = f2bfb(u);
                }
            }
    }
    __syncthreads();

    // ---- matmul2 (K=128): u @ w_e2 ----
    f32x4 acc2[4][2];
#pragma unroll
    for (int mf = 0; mf < 4; ++mf)
#pragma unroll
        for (int nf = 0; nf < 2; ++nf) acc2[mf][nf] = (f32x4){0.f,0.f,0.f,0.f};

    for (int kt = 0; kt < 4; ++kt) {
        int k0 = kt * 32;
        short8 a[4];
#pragma unroll
        for (int mf = 0; mf < 4; ++mf)
            a[mf] = *(const short8*)(xs + uaddr(mf * 16 + l16, k0 + lk * 8));
        short8 b0 = *(const short8*)(wt2 + ((size_t)(colbase + l16)      * 128 + k0 + lk * 8));
        short8 b1 = *(const short8*)(wt2 + ((size_t)(colbase + 16 + l16) * 128 + k0 + lk * 8));
#pragma unroll
        for (int mf = 0; mf < 4; ++mf) {
            acc2[mf][0] = __builtin_amdgcn_mfma_f32_16x16x32_bf16(a[mf], b0, acc2[mf][0], 0, 0, 0);
            acc2[mf][1] = __builtin_amdgcn_mfma_f32_16x16x32_bf16(a[mf], b1, acc2[mf][1], 0, 0, 0);
        }
    }

    // ---- residual + LN + store ----
    float xv[4][2][4];
    {
        float be2[2] = { ld<F32>(b_e2, colbase + l16), ld<F32>(b_e2, colbase + 16 + l16) };
#pragma unroll
        for (int mf = 0; mf < 4; ++mf)
#pragma unroll
            for (int nf = 0; nf < 2; ++nf) {
                int col = colbase + nf * 16 + l16;
#pragma unroll
                for (int rr = 0; rr < 4; ++rr) {
                    int row = mf * 16 + lk * 4 + rr;
                    unsigned short eb = *(const unsigned short*)(xs + xaddr(row, col));
                    xv[mf][nf][rr] = bfb2f(eb) + acc2[mf][nf][rr] + be2[nf];
                }
            }
    }
    // per-row sums across the wave's 32 cols, then LDS-combine across waves
#pragma unroll
    for (int mf = 0; mf < 4; ++mf)
#pragma unroll
        for (int rr = 0; rr < 4; ++rr) {
            float v0 = xv[mf][0][rr], v1 = xv[mf][1][rr];
            float s = v0 + v1;
            float s2 = v0 * v0 + v1 * v1;
#pragma unroll
            for (int off = 1; off < 16; off <<= 1) {
                s  += __shfl_xor(s, off, 16);
                s2 += __shfl_xor(s2, off, 16);
            }
            if (l16 == 0) {
                int row = mf * 16 + lk * 4 + rr;
                atomicAdd(&sm_s[row], s);
                atomicAdd(&sm_s2[row], s2);
            }
        }
    __syncthreads();
    if (tid < BM) {
        float mu = sm_s[tid] * (1.f / 128.f);
        float var = sm_s2[tid] * (1.f / 128.f) - mu * mu;
        sm_mu[tid] = mu;
        sm_rs[tid] = rsqrtf(var + EPSLN);
    }
    __syncthreads();
    {
        float ge[2]  = { ld<F32>(g_e, colbase + l16),  ld<F32>(g_e, colbase + 16 + l16) };
        float bte[2] = { ld<F32>(bt_e, colbase + l16), ld<F32>(bt_e, colbase + 16 + l16) };
#pragma unroll
        for (int mf = 0; mf < 4; ++mf)
#pragma unroll
            for (int nf = 0; nf < 2; ++nf) {
                int col = colbase + nf * 16 + l16;
#pragma unroll
                for (int rr = 0; rr < 4; ++rr) {
                    int row = mf * 16 + lk * 4 + rr;
                    int eid = base + row;
                    float o = (xv[mf][nf][rr] - sm_mu[row]) * sm_rs[row] * ge[nf] + bte[nf];
                    if (eid < ne) st<F32>(out, obase + (size_t)eid * 128 + col, o);
                }
            }
    }
}
__global__ void __launch_bounds__(256, 3) edge_mega_kernel(
    const int* __restrict__ flag,
    const void* e, const int* src, const int* dst,
    const bf16* p_src, const bf16* p_dst, const float* p_msg,
    const unsigned short* wtg, const unsigned short* wt1, const unsigned short* wt2,
    const void* b_eg, const void* b_e1, const void* b_e2,
    const void* g_e, const void* bt_e,
    float* agg, void* out, size_t obase, int ne)
{
    if (*flag) edge_mega_body<1>(e, src, dst, p_src, p_dst, p_msg, wtg, wt1, wt2,
                                 b_eg, b_e1, b_e2, g_e, bt_e, agg, out, obase, ne);
    else       edge_mega_body<0>(e, src, dst, p_src, p_dst, p_msg, wtg, wt1, wt2,
                                 b_eg, b_e1, b_e2, g_e, bt_e, agg, out, obase, ne);
}

// ---------------------------------------------------------------------------
// node update (round-2, known good)
// ---------------------------------------------------------------------------
template<int F32>
__device__ void node_update_body(
    const void* h, const float* __restrict__ agg,
    const void* w_n1, const void* b_n1, const void* w_n2, const void* b_n2,
    const void* g_n, const void* bt_n, void* out, int n)
{
    __shared__ float xs[NBLK][2 * DIMN];
    __shared__ float u1[NBLK][DIMN];
    __shared__ float xv[NBLK][DIMN];
    __shared__ float mu_s[NBLK], rs_s[NBLK];
    const int base = blockIdx.x * NBLK;
    const int tid = threadIdx.x;

    for (int idx = tid; idx < NBLK * DIMN; idx += 128) {
        int r = idx >> 7, c = idx & 127;
        int row = base + r;
        xs[r][c]        = (row < n) ? ld<F32>(h, (size_t)row * DIMN + c) : 0.f;
        xs[r][DIMN + c] = (row < n) ? agg[(size_t)row * DIMN + c] : 0.f;
    }
    __syncthreads();

    const int j = tid;
    float acc[NBLK];
#pragma unroll
    for (int r = 0; r < NBLK; ++r) acc[r] = 0.f;
#pragma unroll 4
    for (int k = 0; k < 2 * DIMN; ++k) {
        float w = ld<F32>(w_n1, k * DIMN + j);
#pragma unroll
        for (int r = 0; r < NBLK; ++r) acc[r] += xs[r][k] * w;
    }
    float b1 = ld<F32>(b_n1, j);
#pragma unroll
    for (int r = 0; r < NBLK; ++r) {
        float u = acc[r] + b1;
        u1[r][j] = u * sigm(u);
    }
    __syncthreads();

#pragma unroll
    for (int r = 0; r < NBLK; ++r) acc[r] = 0.f;
#pragma unroll 4
    for (int k = 0; k < DIMN; ++k) {
        float w = ld<F32>(w_n2, k * DIMN + j);
#pragma unroll
        for (int r = 0; r < NBLK; ++r) acc[r] += u1[r][k] * w;
    }
    float b2 = ld<F32>(b_n2, j);
#pragma unroll
    for (int r = 0; r < NBLK; ++r) {
        xv[r][j] = xs[r][j] + acc[r] + b2;
    }
    __syncthreads();

    {
        int r = tid >> 4, l = tid & 15;
        float s = 0.f, s2 = 0.f;
        for (int c = l; c < DIMN; c += 16) {
            float v = xv[r][c];
            s += v; s2 += v * v;
        }
#pragma unroll
        for (int off = 8; off > 0; off >>= 1) {
            s  += __shfl_down(s, off, 16);
            s2 += __shfl_down(s2, off, 16);
        }
        if (l == 0) {
            float mu = s / DIMN;
            float var = s2 / DIMN - mu * mu;
            mu_s[r] = mu;
            rs_s[r] = rsqrtf(var + EPSLN);
        }
    }
    __syncthreads();

    float gg = ld<F32>(g_n, j), bb = ld<F32>(bt_n, j);
#pragma unroll
    for (int r = 0; r < NBLK; ++r) {
        int row = base + r;
        if (row < n)
            st<F32>(out, (size_t)row * DIMN + j, (xv[r][j] - mu_s[r]) * rs_s[r] * gg + bb);
    }
}
__global__ void __launch_bounds__(128) node_update_kernel(
    const int* __restrict__ flag,
    const void* h, const float* agg,
    const void* w_n1, const void* b_n1, const void* w_n2, const void* b_n2,
    const void* g_n, const void* bt_n, void* out, int n)
{
    if (*flag) node_update_body<1>(h, agg, w_n1, b_n1, w_n2, b_n2, g_n, bt_n, out, n);
    else       node_update_body<0>(h, agg, w_n1, b_n1, w_n2, b_n2, g_n, bt_n, out, n);
}

// ---------------------------------------------------------------------------
extern "C" void kernel_launch(void* const* d_in, const int* in_sizes, int n_in,
                              void* d_out, int out_size, void* d_ws, size_t ws_size,
                              hipStream_t stream)
{
    const void* h     = d_in[0];
    const void* e     = d_in[1];
    const int*  src   = (const int*)d_in[2];
    const int*  dst   = (const int*)d_in[3];
    const void* w_src = d_in[4];
    const void* b_src = d_in[5];
    const void* w_dst = d_in[6];
    const void* b_dst = d_in[7];
    const void* w_eg  = d_in[8];
    const void* b_eg  = d_in[9];
    const void* w_msg = d_in[10];
    const void* b_msg = d_in[11];
    const void* w_n1  = d_in[12];
    const void* b_n1  = d_in[13];
    const void* w_n2  = d_in[14];
    const void* b_n2  = d_in[15];
    const void* w_e1  = d_in[16];
    const void* b_e1  = d_in[17];
    const void* w_e2  = d_in[18];
    const void* b_e2  = d_in[19];
    const void* g_n   = d_in[20];
    const void* bt_n  = d_in[21];
    const void* g_e   = d_in[22];
    const void* bt_e  = d_in[23];

    const int n  = in_sizes[0] / DIMN;   // 40000
    const int ne = in_sizes[1] / DIMN;   // 640000

    // workspace layout
    char* ws = (char*)d_ws;
    bf16*  p_src = (bf16*)ws;                          ws += (size_t)n * DIMN * 2;
    bf16*  p_dst = (bf16*)ws;                          ws += (size_t)n * DIMN * 2;
    float* p_msg = (float*)ws;                         ws += (size_t)n * DIMN * 4;
    float* agg   = (float*)ws;                         ws += (size_t)n * DIMN * 4;
    int*   flag  = (int*)ws;                           ws += 256;
    unsigned short* wtg = (unsigned short*)ws;         ws += 128 * 128 * 2;
    unsigned short* wt2 = (unsigned short*)ws;         ws += 128 * 128 * 2;
    unsigned short* wt1 = (unsigned short*)ws;         ws += 128 * 384 * 2;

    hipMemsetAsync(agg, 0, (size_t)n * DIMN * sizeof(float), stream);

    detect_dtype_kernel<<<1, 64, 0, stream>>>((const uint32_t*)h, flag);

    int nb_n = (n + NBLK - 1) / NBLK;
    int nb_e64 = (ne + BM - 1) / BM;

    node_proj_kernel<<<nb_n, 128, 0, stream>>>(
        flag, h, w_src, b_src, w_dst, b_dst, w_msg, b_msg, p_src, p_dst, p_msg, n);

    prep_weights_kernel<<<192, 256, 0, stream>>>(flag, w_eg, w_e1, w_e2, wtg, wt1, wt2);

    edge_mega_kernel<<<nb_e64, 256, 0, stream>>>(
        flag, e, src, dst, p_src, p_dst, p_msg, wtg, wt1, wt2,
        b_eg, b_e1, b_e2, g_e, bt_e, agg, d_out, (size_t)n * DIMN, ne);

    node_update_kernel<<<nb_n, 128, 0, stream>>>(
        flag, h, agg, w_n1, b_n1, w_n2, b_n2, g_n, bt_n, d_out, n);
}

// Round 4
// 1088.614 us; speedup vs baseline: 3.5137x; 1.8487x over previous
//
#include <hip/hip_runtime.h>
#include <hip/hip_bf16.h>
#include <stdint.h>

typedef __hip_bfloat16 bf16;
typedef __attribute__((ext_vector_type(8))) short short8;
typedef __attribute__((ext_vector_type(4))) float f32x4;

#define DIMN 128
#define NBLK 8
#define BM 64
#define EPSLN 1e-5f

__device__ __forceinline__ float b2f(bf16 x) { return __bfloat162float(x); }
__device__ __forceinline__ bf16  f2b(float x) { return __float2bfloat16(x); }
__device__ __forceinline__ float sigm(float x) { return 1.0f / (1.0f + __expf(-x)); }

__device__ __forceinline__ float bfb2f(unsigned short u) {
    union { uint32_t i; float f; } v; v.i = ((uint32_t)u) << 16; return v.f;
}
__device__ __forceinline__ unsigned short f2bfb(float f) {
    union { float f; uint32_t i; } v; v.f = f;
    uint32_t x = v.i;
    return (unsigned short)((x + 0x7FFFu + ((x >> 16) & 1u)) >> 16);
}

template<int F32>
__device__ __forceinline__ float ld(const void* p, size_t i) {
    if (F32) return ((const float*)p)[i];
    else     return bfb2f(((const unsigned short*)p)[i]);
}
template<int F32>
__device__ __forceinline__ void st(void* p, size_t i, float v) {
    if (F32) ((float*)p)[i] = v;
    else     ((unsigned short*)p)[i] = f2bfb(v);
}
template<int F32>
__device__ __forceinline__ void load8(const void* p, size_t elem, float v[8]) {
    if (F32) {
        const float4* q = (const float4*)((const float*)p + elem);
        float4 a = q[0], b = q[1];
        v[0]=a.x; v[1]=a.y; v[2]=a.z; v[3]=a.w;
        v[4]=b.x; v[5]=b.y; v[6]=b.z; v[7]=b.w;
    } else {
        short8 s = *(const short8*)((const short*)p + elem);
#pragma unroll
        for (int j = 0; j < 8; ++j) v[j] = bfb2f((unsigned short)s[j]);
    }
}

// X tile: [64 rows][384 k] bf16, row stride 768 B, XOR-swizzled 16B units
__device__ __forceinline__ uint32_t xaddr(int r, int k) {
    return (uint32_t)(r * 768 + ((k * 2) ^ ((r & 7) << 4)));
}
// u tile lives in X's segment-2 bytes [512,768) per row
__device__ __forceinline__ uint32_t uaddr(int r, int k) {
    return (uint32_t)(r * 768 + 512 + ((k * 2) ^ ((r & 7) << 4)));
}

// ---------------------------------------------------------------------------
// dtype detector (low 16 bits of f32 words look uniform; packed-bf16 doesn't)
// ---------------------------------------------------------------------------
__global__ void detect_dtype_kernel(const uint32_t* __restrict__ w, int* __restrict__ flag) {
    if (threadIdx.x == 0 && blockIdx.x == 0) {
        int c = 0;
        for (int i = 0; i < 64; ++i) {
            uint32_t lo = w[i] & 0xFFFFu;
            int e = (int)((lo >> 7) & 0xFF);
            if (e >= 90 && e <= 140) ++c;
        }
        *flag = (c < 32) ? 1 : 0;   // 1 => float32 tensors
    }
}

// ---------------------------------------------------------------------------
// weight prep: transpose + bf16-ify  wT[c][k] = w[k][c]
// ---------------------------------------------------------------------------
template<int F32>
__device__ void prep_body(const void* w_eg, const void* w_e1, const void* w_e2,
                          unsigned short* wtg, unsigned short* wt1, unsigned short* wt2)
{
    int idx = blockIdx.x * 256 + threadIdx.x;
    if (idx < 128 * 384) {
        int c = idx / 384, k = idx % 384;
        wt1[idx] = f2bfb(ld<F32>(w_e1, (size_t)k * 128 + c));
    }
    if (idx < 128 * 128) {
        int c = idx >> 7, k = idx & 127;
        wtg[idx] = f2bfb(ld<F32>(w_eg, (size_t)k * 128 + c));
        wt2[idx] = f2bfb(ld<F32>(w_e2, (size_t)k * 128 + c));
    }
}
__global__ void __launch_bounds__(256) prep_weights_kernel(
    const int* __restrict__ flag,
    const void* w_eg, const void* w_e1, const void* w_e2,
    unsigned short* wtg, unsigned short* wt1, unsigned short* wt2)
{
    if (*flag) prep_body<1>(w_eg, w_e1, w_e2, wtg, wt1, wt2);
    else       prep_body<0>(w_eg, w_e1, w_e2, wtg, wt1, wt2);
}

// ---------------------------------------------------------------------------
// node projections — LDS hoisted to __global__ (single allocation)
// ---------------------------------------------------------------------------
template<int F32>
__device__ void node_proj_body(
    float (*xs)[DIMN],
    const void* h, const void* w_src, const void* b_src,
    const void* w_dst, const void* b_dst, const void* w_msg, const void* b_msg,
    bf16* __restrict__ p_src, bf16* __restrict__ p_dst, float* __restrict__ p_msg, int n)
{
    const int base = blockIdx.x * NBLK;
    const int tid = threadIdx.x;

    for (int idx = tid; idx < NBLK * DIMN; idx += 128) {
        int r = idx >> 7, c = idx & 127;
        int row = base + r;
        xs[r][c] = (row < n) ? ld<F32>(h, (size_t)row * DIMN + c) : 0.f;
    }
    __syncthreads();

    const int j = tid;
    float a0[NBLK], a1[NBLK], a2[NBLK];
#pragma unroll
    for (int r = 0; r < NBLK; ++r) { a0[r] = 0.f; a1[r] = 0.f; a2[r] = 0.f; }

#pragma unroll 4
    for (int k = 0; k < DIMN; ++k) {
        float ws_ = ld<F32>(w_src, k * DIMN + j);
        float wd_ = ld<F32>(w_dst, k * DIMN + j);
        float wm_ = ld<F32>(w_msg, k * DIMN + j);
#pragma unroll
        for (int r = 0; r < NBLK; ++r) {
            float x = xs[r][k];
            a0[r] += x * ws_; a1[r] += x * wd_; a2[r] += x * wm_;
        }
    }

    float bs = ld<F32>(b_src, j), bd = ld<F32>(b_dst, j), bm = ld<F32>(b_msg, j);
#pragma unroll
    for (int r = 0; r < NBLK; ++r) {
        int row = base + r;
        if (row < n) {
            size_t o = (size_t)row * DIMN + j;
            p_src[o] = f2b(a0[r] + bs);
            p_dst[o] = f2b(a1[r] + bd);
            p_msg[o] = a2[r] + bm;
        }
    }
}
__global__ void __launch_bounds__(128) node_proj_kernel(
    const int* __restrict__ flag,
    const void* h, const void* w_src, const void* b_src,
    const void* w_dst, const void* b_dst, const void* w_msg, const void* b_msg,
    bf16* p_src, bf16* p_dst, float* p_msg, int n)
{
    __shared__ float xs[NBLK][DIMN];
    if (*flag) node_proj_body<1>(xs, h, w_src, b_src, w_dst, b_dst, w_msg, b_msg, p_src, p_dst, p_msg, n);
    else       node_proj_body<0>(xs, h, w_src, b_src, w_dst, b_dst, w_msg, b_msg, p_src, p_dst, p_msg, n);
}

// ---------------------------------------------------------------------------
// fused edge mega-kernel (MFMA) — LDS hoisted to __global__ (single allocation)
// ---------------------------------------------------------------------------
template<int F32>
__device__ void edge_mega_body(
    char* xs, int* sidx, int* didx,
    float* sm_s, float* sm_s2, float* sm_mu, float* sm_rs,
    const void* e,
    const int* __restrict__ src, const int* __restrict__ dst,
    const bf16* __restrict__ p_src, const bf16* __restrict__ p_dst,
    const float* __restrict__ p_msg,
    const unsigned short* __restrict__ wtg,   // [128][128]
    const unsigned short* __restrict__ wt1,   // [128][384]
    const unsigned short* __restrict__ wt2,   // [128][128]
    const void* b_eg, const void* b_e1, const void* b_e2,
    const void* g_e, const void* bt_e,
    float* __restrict__ agg, void* out, size_t obase, int ne)
{
    const int tid = threadIdx.x;
    const int base = blockIdx.x * BM;

    if (tid < BM) {
        int eid = base + tid;
        sidx[tid] = (eid < ne) ? src[eid] : 0;
        didx[tid] = (eid < ne) ? dst[eid] : 0;
        sm_s[tid] = 0.f; sm_s2[tid] = 0.f;
    }
    __syncthreads();

    // ---- stage X = [e | p_msg[src] | p_msg[dst]] as bf16, swizzled ----
    for (int idx = tid; idx < BM * 48; idx += 256) {
        int r = idx / 48;
        int kc = (idx % 48) * 8;          // element offset in [0,384)
        int eid = base + r;
        float v[8];
        if (eid < ne) {
            if (kc < 128)       load8<F32>(e, (size_t)eid * 128 + kc, v);
            else if (kc < 256)  load8<1>(p_msg, (size_t)sidx[r] * 128 + (kc - 128), v);
            else                load8<1>(p_msg, (size_t)didx[r] * 128 + (kc - 256), v);
        } else {
#pragma unroll
            for (int j = 0; j < 8; ++j) v[j] = 0.f;
        }
        short8 pk;
#pragma unroll
        for (int j = 0; j < 8; ++j) pk[j] = (short)f2bfb(v[j]);
        *(short8*)(xs + xaddr(r, kc)) = pk;
    }
    __syncthreads();

    const int lane = tid & 63;
    const int wv = tid >> 6;            // wave 0..3 owns cols [wv*32, wv*32+32)
    const int l16 = lane & 15;
    const int lk = lane >> 4;           // 0..3
    const int colbase = wv * 32;

    f32x4 acc1[4][2], accg[4][2];
#pragma unroll
    for (int mf = 0; mf < 4; ++mf)
#pragma unroll
        for (int nf = 0; nf < 2; ++nf) {
            acc1[mf][nf] = (f32x4){0.f,0.f,0.f,0.f};
            accg[mf][nf] = (f32x4){0.f,0.f,0.f,0.f};
        }

    // ---- matmul1 (K=384) with gate matmul fused into K-steps 0..3 ----
    for (int kt = 0; kt < 12; ++kt) {
        int k0 = kt * 32;
        short8 a[4];
#pragma unroll
        for (int mf = 0; mf < 4; ++mf)
            a[mf] = *(const short8*)(xs + xaddr(mf * 16 + l16, k0 + lk * 8));
        short8 b0 = *(const short8*)(wt1 + ((size_t)(colbase + l16)      * 384 + k0 + lk * 8));
        short8 b1 = *(const short8*)(wt1 + ((size_t)(colbase + 16 + l16) * 384 + k0 + lk * 8));
#pragma unroll
        for (int mf = 0; mf < 4; ++mf) {
            acc1[mf][0] = __builtin_amdgcn_mfma_f32_16x16x32_bf16(a[mf], b0, acc1[mf][0], 0, 0, 0);
            acc1[mf][1] = __builtin_amdgcn_mfma_f32_16x16x32_bf16(a[mf], b1, acc1[mf][1], 0, 0, 0);
        }
        if (kt < 4) {
            short8 g0 = *(const short8*)(wtg + ((size_t)(colbase + l16)      * 128 + k0 + lk * 8));
            short8 g1 = *(const short8*)(wtg + ((size_t)(colbase + 16 + l16) * 128 + k0 + lk * 8));
#pragma unroll
            for (int mf = 0; mf < 4; ++mf) {
                accg[mf][0] = __builtin_amdgcn_mfma_f32_16x16x32_bf16(a[mf], g0, accg[mf][0], 0, 0, 0);
                accg[mf][1] = __builtin_amdgcn_mfma_f32_16x16x32_bf16(a[mf], g1, accg[mf][1], 0, 0, 0);
            }
        }
    }

    // ---- gate epilogue: sigmoid * msg, atomic scatter into agg ----
    {
        float bge[2] = { ld<F32>(b_eg, colbase + l16), ld<F32>(b_eg, colbase + 16 + l16) };
#pragma unroll
        for (int mf = 0; mf < 4; ++mf)
#pragma unroll
            for (int nf = 0; nf < 2; ++nf) {
                int col = colbase + nf * 16 + l16;
#pragma unroll
                for (int rr = 0; rr < 4; ++rr) {
                    int row = mf * 16 + lk * 4 + rr;
                    int eid = base + row;
                    int s = sidx[row], d = didx[row];
                    float g = accg[mf][nf][rr] + bge[nf]
                            + bfb2f(((const unsigned short*)p_src)[(size_t)s * 128 + col])
                            + bfb2f(((const unsigned short*)p_dst)[(size_t)d * 128 + col]);
                    unsigned short pm = *(const unsigned short*)(xs + (row * 768 + (((128 + col) * 2) ^ ((row & 7) << 4))));
                    float m = sigm(g) * bfb2f(pm);
                    if (eid < ne) atomicAdd(&agg[(size_t)d * 128 + col], m);
                }
            }
    }
    __syncthreads();   // all reads of X seg2 done (matmul1 + gate) before u overwrite

    // ---- silu, write u into X seg2 (bf16, swizzled) ----
    {
        float be1[2] = { ld<F32>(b_e1, colbase + l16), ld<F32>(b_e1, colbase + 16 + l16) };
#pragma unroll
        for (int mf = 0; mf < 4; ++mf)
#pragma unroll
            for (int nf = 0; nf < 2; ++nf) {
                int col = colbase + nf * 16 + l16;
#pragma unroll
                for (int rr = 0; rr < 4; ++rr) {
                    int row = mf * 16 + lk * 4 + rr;
                    float u = acc1[mf][nf][rr] + be1[nf];
                    u = u * sigm(u);
                    *(unsigned short*)(xs + uaddr(row, col)) = f2bfb(u);
                }
            }
    }
    __syncthreads();

    // ---- matmul2 (K=128): u @ w_e2 ----
    f32x4 acc2[4][2];
#pragma unroll
    for (int mf = 0; mf < 4; ++mf)
#pragma unroll
        for (int nf = 0; nf < 2; ++nf) acc2[mf][nf] = (f32x4){0.f,0.f,0.f,0.f};

    for (int kt = 0; kt < 4; ++kt) {
        int k0 = kt * 32;
        short8 a[4];
#pragma unroll
        for (int mf = 0; mf < 4; ++mf)
            a[mf] = *(const short8*)(xs + uaddr(mf * 16 + l16, k0 + lk * 8));
        short8 b0 = *(const short8*)(wt2 + ((size_t)(colbase + l16)      * 128 + k0 + lk * 8));
        short8 b1 = *(const short8*)(wt2 + ((size_t)(colbase + 16 + l16) * 128 + k0 + lk * 8));
#pragma unroll
        for (int mf = 0; mf < 4; ++mf) {
            acc2[mf][0] = __builtin_amdgcn_mfma_f32_16x16x32_bf16(a[mf], b0, acc2[mf][0], 0, 0, 0);
            acc2[mf][1] = __builtin_amdgcn_mfma_f32_16x16x32_bf16(a[mf], b1, acc2[mf][1], 0, 0, 0);
        }
    }

    // ---- residual + LN + store ----
    float xv[4][2][4];
    {
        float be2[2] = { ld<F32>(b_e2, colbase + l16), ld<F32>(b_e2, colbase + 16 + l16) };
#pragma unroll
        for (int mf = 0; mf < 4; ++mf)
#pragma unroll
            for (int nf = 0; nf < 2; ++nf) {
                int col = colbase + nf * 16 + l16;
#pragma unroll
                for (int rr = 0; rr < 4; ++rr) {
                    int row = mf * 16 + lk * 4 + rr;
                    unsigned short eb = *(const unsigned short*)(xs + xaddr(row, col));
                    xv[mf][nf][rr] = bfb2f(eb) + acc2[mf][nf][rr] + be2[nf];
                }
            }
    }
#pragma unroll
    for (int mf = 0; mf < 4; ++mf)
#pragma unroll
        for (int rr = 0; rr < 4; ++rr) {
            float v0 = xv[mf][0][rr], v1 = xv[mf][1][rr];
            float s = v0 + v1;
            float s2 = v0 * v0 + v1 * v1;
#pragma unroll
            for (int off = 1; off < 16; off <<= 1) {
                s  += __shfl_xor(s, off, 16);
                s2 += __shfl_xor(s2, off, 16);
            }
            if (l16 == 0) {
                int row = mf * 16 + lk * 4 + rr;
                atomicAdd(&sm_s[row], s);
                atomicAdd(&sm_s2[row], s2);
            }
        }
    __syncthreads();
    if (tid < BM) {
        float mu = sm_s[tid] * (1.f / 128.f);
        float var = sm_s2[tid] * (1.f / 128.f) - mu * mu;
        sm_mu[tid] = mu;
        sm_rs[tid] = rsqrtf(var + EPSLN);
    }
    __syncthreads();
    {
        float ge[2]  = { ld<F32>(g_e, colbase + l16),  ld<F32>(g_e, colbase + 16 + l16) };
        float bte[2] = { ld<F32>(bt_e, colbase + l16), ld<F32>(bt_e, colbase + 16 + l16) };
#pragma unroll
        for (int mf = 0; mf < 4; ++mf)
#pragma unroll
            for (int nf = 0; nf < 2; ++nf) {
                int col = colbase + nf * 16 + l16;
#pragma unroll
                for (int rr = 0; rr < 4; ++rr) {
                    int row = mf * 16 + lk * 4 + rr;
                    int eid = base + row;
                    float o = (xv[mf][nf][rr] - sm_mu[row]) * sm_rs[row] * ge[nf] + bte[nf];
                    if (eid < ne) st<F32>(out, obase + (size_t)eid * 128 + col, o);
                }
            }
    }
}
__global__ void __launch_bounds__(256, 3) edge_mega_kernel(
    const int* __restrict__ flag,
    const void* e, const int* src, const int* dst,
    const bf16* p_src, const bf16* p_dst, const float* p_msg,
    const unsigned short* wtg, const unsigned short* wt1, const unsigned short* wt2,
    const void* b_eg, const void* b_e1, const void* b_e2,
    const void* g_e, const void* bt_e,
    float* agg, void* out, size_t obase, int ne)
{
    __shared__ short xs_raw[BM * 384];      // 48 KB, swizzled; seg2 reused for u
    __shared__ int sidx[BM], didx[BM];
    __shared__ float sm_s[BM], sm_s2[BM], sm_mu[BM], sm_rs[BM];
    char* xs = (char*)xs_raw;
    if (*flag) edge_mega_body<1>(xs, sidx, didx, sm_s, sm_s2, sm_mu, sm_rs,
                                 e, src, dst, p_src, p_dst, p_msg, wtg, wt1, wt2,
                                 b_eg, b_e1, b_e2, g_e, bt_e, agg, out, obase, ne);
    else       edge_mega_body<0>(xs, sidx, didx, sm_s, sm_s2, sm_mu, sm_rs,
                                 e, src, dst, p_src, p_dst, p_msg, wtg, wt1, wt2,
                                 b_eg, b_e1, b_e2, g_e, bt_e, agg, out, obase, ne);
}

// ---------------------------------------------------------------------------
// node update — LDS hoisted to __global__ (single allocation)
// ---------------------------------------------------------------------------
template<int F32>
__device__ void node_update_body(
    float (*xs)[2 * DIMN], float (*u1)[DIMN], float (*xv)[DIMN],
    float* mu_s, float* rs_s,
    const void* h, const float* __restrict__ agg,
    const void* w_n1, const void* b_n1, const void* w_n2, const void* b_n2,
    const void* g_n, const void* bt_n, void* out, int n)
{
    const int base = blockIdx.x * NBLK;
    const int tid = threadIdx.x;

    for (int idx = tid; idx < NBLK * DIMN; idx += 128) {
        int r = idx >> 7, c = idx & 127;
        int row = base + r;
        xs[r][c]        = (row < n) ? ld<F32>(h, (size_t)row * DIMN + c) : 0.f;
        xs[r][DIMN + c] = (row < n) ? agg[(size_t)row * DIMN + c] : 0.f;
    }
    __syncthreads();

    const int j = tid;
    float acc[NBLK];
#pragma unroll
    for (int r = 0; r < NBLK; ++r) acc[r] = 0.f;
#pragma unroll 4
    for (int k = 0; k < 2 * DIMN; ++k) {
        float w = ld<F32>(w_n1, k * DIMN + j);
#pragma unroll
        for (int r = 0; r < NBLK; ++r) acc[r] += xs[r][k] * w;
    }
    float b1 = ld<F32>(b_n1, j);
#pragma unroll
    for (int r = 0; r < NBLK; ++r) {
        float u = acc[r] + b1;
        u1[r][j] = u * sigm(u);
    }
    __syncthreads();

#pragma unroll
    for (int r = 0; r < NBLK; ++r) acc[r] = 0.f;
#pragma unroll 4
    for (int k = 0; k < DIMN; ++k) {
        float w = ld<F32>(w_n2, k * DIMN + j);
#pragma unroll
        for (int r = 0; r < NBLK; ++r) acc[r] += u1[r][k] * w;
    }
    float b2 = ld<F32>(b_n2, j);
#pragma unroll
    for (int r = 0; r < NBLK; ++r) {
        xv[r][j] = xs[r][j] + acc[r] + b2;
    }
    __syncthreads();

    {
        int r = tid >> 4, l = tid & 15;
        float s = 0.f, s2 = 0.f;
        for (int c = l; c < DIMN; c += 16) {
            float v = xv[r][c];
            s += v; s2 += v * v;
        }
#pragma unroll
        for (int off = 8; off > 0; off >>= 1) {
            s  += __shfl_down(s, off, 16);
            s2 += __shfl_down(s2, off, 16);
        }
        if (l == 0) {
            float mu = s / DIMN;
            float var = s2 / DIMN - mu * mu;
            mu_s[r] = mu;
            rs_s[r] = rsqrtf(var + EPSLN);
        }
    }
    __syncthreads();

    float gg = ld<F32>(g_n, j), bb = ld<F32>(bt_n, j);
#pragma unroll
    for (int r = 0; r < NBLK; ++r) {
        int row = base + r;
        if (row < n)
            st<F32>(out, (size_t)row * DIMN + j, (xv[r][j] - mu_s[r]) * rs_s[r] * gg + bb);
    }
}
__global__ void __launch_bounds__(128) node_update_kernel(
    const int* __restrict__ flag,
    const void* h, const float* agg,
    const void* w_n1, const void* b_n1, const void* w_n2, const void* b_n2,
    const void* g_n, const void* bt_n, void* out, int n)
{
    __shared__ float xs[NBLK][2 * DIMN];
    __shared__ float u1[NBLK][DIMN];
    __shared__ float xv[NBLK][DIMN];
    __shared__ float mu_s[NBLK], rs_s[NBLK];
    if (*flag) node_update_body<1>(xs, u1, xv, mu_s, rs_s, h, agg, w_n1, b_n1, w_n2, b_n2, g_n, bt_n, out, n);
    else       node_update_body<0>(xs, u1, xv, mu_s, rs_s, h, agg, w_n1, b_n1, w_n2, b_n2, g_n, bt_n, out, n);
}

// ---------------------------------------------------------------------------
extern "C" void kernel_launch(void* const* d_in, const int* in_sizes, int n_in,
                              void* d_out, int out_size, void* d_ws, size_t ws_size,
                              hipStream_t stream)
{
    const void* h     = d_in[0];
    const void* e     = d_in[1];
    const int*  src   = (const int*)d_in[2];
    const int*  dst   = (const int*)d_in[3];
    const void* w_src = d_in[4];
    const void* b_src = d_in[5];
    const void* w_dst = d_in[6];
    const void* b_dst = d_in[7];
    const void* w_eg  = d_in[8];
    const void* b_eg  = d_in[9];
    const void* w_msg = d_in[10];
    const void* b_msg = d_in[11];
    const void* w_n1  = d_in[12];
    const void* b_n1  = d_in[13];
    const void* w_n2  = d_in[14];
    const void* b_n2  = d_in[15];
    const void* w_e1  = d_in[16];
    const void* b_e1  = d_in[17];
    const void* w_e2  = d_in[18];
    const void* b_e2  = d_in[19];
    const void* g_n   = d_in[20];
    const void* bt_n  = d_in[21];
    const void* g_e   = d_in[22];
    const void* bt_e  = d_in[23];

    const int n  = in_sizes[0] / DIMN;   // 40000
    const int ne = in_sizes[1] / DIMN;   // 640000

    // workspace layout
    char* ws = (char*)d_ws;
    bf16*  p_src = (bf16*)ws;                          ws += (size_t)n * DIMN * 2;
    bf16*  p_dst = (bf16*)ws;                          ws += (size_t)n * DIMN * 2;
    float* p_msg = (float*)ws;                         ws += (size_t)n * DIMN * 4;
    float* agg   = (float*)ws;                         ws += (size_t)n * DIMN * 4;
    int*   flag  = (int*)ws;                           ws += 256;
    unsigned short* wtg = (unsigned short*)ws;         ws += 128 * 128 * 2;
    unsigned short* wt2 = (unsigned short*)ws;         ws += 128 * 128 * 2;
    unsigned short* wt1 = (unsigned short*)ws;         ws += 128 * 384 * 2;

    hipMemsetAsync(agg, 0, (size_t)n * DIMN * sizeof(float), stream);

    detect_dtype_kernel<<<1, 64, 0, stream>>>((const uint32_t*)h, flag);

    int nb_n = (n + NBLK - 1) / NBLK;
    int nb_e64 = (ne + BM - 1) / BM;

    node_proj_kernel<<<nb_n, 128, 0, stream>>>(
        flag, h, w_src, b_src, w_dst, b_dst, w_msg, b_msg, p_src, p_dst, p_msg, n);

    prep_weights_kernel<<<192, 256, 0, stream>>>(flag, w_eg, w_e1, w_e2, wtg, wt1, wt2);

    edge_mega_kernel<<<nb_e64, 256, 0, stream>>>(
        flag, e, src, dst, p_src, p_dst, p_msg, wtg, wt1, wt2,
        b_eg, b_e1, b_e2, g_e, bt_e, agg, d_out, (size_t)n * DIMN, ne);

    node_update_kernel<<<nb_n, 128, 0, stream>>>(
        flag, h, agg, w_n1, b_n1, w_n2, b_n2, g_n, bt_n, d_out, n);
}